// Round 8
// baseline (84.437 us; speedup 1.0000x reference)
//
#include <hip/hip_runtime.h>
#include <math.h>

// FOUR waves per sample, one sample per block (block=256). Amplitude i:
//   bits 0..5 -> lane, bits 6..7 -> register (4 float2/lane),
//   bit 8 -> wave bit k8, bit 9 -> wave bit k9  (wv = k8 | (k9<<1)).
// Layers: fused U_q = RX(theta)*RY(enc). CNOT chain = permutation
// src(j) = j ^ ((j&511)<<1)  (bit_b -> bit_b ^ bit_{b-1}).
// q8,q9 gates are fused into the chain exchange (one LDS round trip):
//   new[j] = (U9 U8 psi)[src(j)], rows m8 = k8^r1, m9 = k9^k8.
// Final chain absorbed into prefix-XOR head weights (r7, extended to wave
// bits); final q8,q9 applied via a same-address 4-amp exchange.
// Rationale: kernel is latency-exposed at 4 waves/SIMD (r6 occupancy win,
// r4 pipe-swap neutral). This forces 8 waves/SIMD (VGPR<=64) and halves the
// per-wave dependency chain again.

#define PI_F 3.14159265358979323846f

typedef unsigned v2u __attribute__((ext_vector_type(2)));

#if defined(__has_builtin)
#if __has_builtin(__builtin_amdgcn_permlane16_swap)
#define HAVE_PL16 1
#endif
#if __has_builtin(__builtin_amdgcn_permlane32_swap)
#define HAVE_PL32 1
#endif
#endif

__device__ __forceinline__ float rdlane(float v, int l) {
    return __int_as_float(__builtin_amdgcn_readlane(__float_as_int(v), l));
}
__device__ __forceinline__ float rdfirst(float v) {
    return __int_as_float(__builtin_amdgcn_readfirstlane(__float_as_int(v)));
}

// ---- VALU-pipe lane^mask partner fetch (verified r4-r7, absmax 0) ----
__device__ __forceinline__ float xor1p(float v) {
    return __int_as_float(__builtin_amdgcn_update_dpp(
        0, __float_as_int(v), 0xB1, 0xF, 0xF, true));
}
__device__ __forceinline__ float xor2p(float v) {
    return __int_as_float(__builtin_amdgcn_update_dpp(
        0, __float_as_int(v), 0x4E, 0xF, 0xF, true));
}
__device__ __forceinline__ float xor4p(float v) {   // xor7 ∘ xor3 = xor4
    int t = __builtin_amdgcn_update_dpp(0, __float_as_int(v), 0x1B, 0xF, 0xF, true);
    t = __builtin_amdgcn_update_dpp(0, t, 0x141, 0xF, 0xF, true);
    return __int_as_float(t);
}
__device__ __forceinline__ float xor8p(float v) {   // row_ror:8
    return __int_as_float(__builtin_amdgcn_update_dpp(
        0, __float_as_int(v), 0x128, 0xF, 0xF, true));
}
__device__ __forceinline__ float xor16p(float v, bool hi) {
#ifdef HAVE_PL16
    v2u r = __builtin_amdgcn_permlane16_swap(
        (unsigned)__float_as_int(v), (unsigned)__float_as_int(v), false, false);
    return __int_as_float((int)(hi ? r.x : r.y));
#else
    return __shfl_xor(v, 16);
#endif
}
__device__ __forceinline__ float xor32p(float v, bool hi) {
#ifdef HAVE_PL32
    v2u r = __builtin_amdgcn_permlane32_swap(
        (unsigned)__float_as_int(v), (unsigned)__float_as_int(v), false, false);
    return __int_as_float((int)(hi ? r.x : r.y));
#else
    return __shfl_xor(v, 32);
#endif
}

template<int Q>
__device__ __forceinline__ float lane_xor(float v, bool hi) {
    if constexpr (Q == 0) return xor1p(v);
    else if constexpr (Q == 1) return xor2p(v);
    else if constexpr (Q == 2) return xor4p(v);
    else if constexpr (Q == 3) return xor8p(v);
    else if constexpr (Q == 4) return xor16p(v, hi);
    else return xor32p(v, hi);
}

// ---- packed complex gate core (verified r5-r7, absmax 0) ----
// cgate<false>(v,w) = A v + B w ; cgate<true>(v,w) = conj(A) v - conj(B) w
struct CG { float2 ar2, ai2, br2, bi2; };
__device__ __forceinline__ CG mkcg(float ce, float se, float ct, float s_t) {
    const float ar = ct * ce, ai = -s_t * se, br = -ct * se, bi = -s_t * ce;
    CG g;
    g.ar2 = make_float2(ar, ar); g.ai2 = make_float2(ai, ai);
    g.br2 = make_float2(br, br); g.bi2 = make_float2(bi, bi);
    return g;
}

template<bool NEG>
__device__ __forceinline__ float2 cgate(const CG& g, const float2 v, const float2 w) {
    float2 acc;
    asm("v_pk_mul_f32 %0, %1, %2" : "=v"(acc) : "v"(g.ar2), "v"(v));
    if constexpr (!NEG) {
        asm("v_pk_fma_f32 %0, %1, %2, %0 op_sel:[0,1,0] op_sel_hi:[1,0,1] neg_lo:[0,1,0]"
            : "+v"(acc) : "v"(g.ai2), "v"(v));
        asm("v_pk_fma_f32 %0, %1, %2, %0" : "+v"(acc) : "v"(g.br2), "v"(w));
    } else {
        asm("v_pk_fma_f32 %0, %1, %2, %0 op_sel:[0,1,0] op_sel_hi:[1,0,1] neg_lo:[1,1,0] neg_hi:[1,0,0]"
            : "+v"(acc) : "v"(g.ai2), "v"(v));
        asm("v_pk_fma_f32 %0, %1, %2, %0 neg_lo:[1,0,0] neg_hi:[1,0,0]"
            : "+v"(acc) : "v"(g.br2), "v"(w));
    }
    asm("v_pk_fma_f32 %0, %1, %2, %0 op_sel:[0,1,0] op_sel_hi:[1,0,1] neg_lo:[0,1,0]"
        : "+v"(acc) : "v"(g.bi2), "v"(w));
    return acc;
}

template<int Q>
__device__ __forceinline__ void lane_gate(float2 (&st)[4], int lane,
                                          float ar, float ai, float br, float bi) {
    const bool hi = (lane & (1 << Q)) != 0;
    const float aiL = hi ? -ai : ai;
    const float brL = hi ? -br : br;
    CG g;
    g.ar2 = make_float2(ar, ar);  g.ai2 = make_float2(aiL, aiL);
    g.br2 = make_float2(brL, brL); g.bi2 = make_float2(bi, bi);
    #pragma unroll
    for (int r = 0; r < 4; ++r) {
        float2 p;
        p.x = lane_xor<Q>(st[r].x, hi);
        p.y = lane_xor<Q>(st[r].y, hi);
        st[r] = cgate<false>(g, st[r], p);
    }
}

template<int RB>
__device__ __forceinline__ void reg_gate(float2 (&st)[4], const CG& g) {
    #pragma unroll
    for (int r = 0; r < 4; ++r) {
        if ((r & RB) == 0) {
            const int r1 = r | RB;
            const float2 v0 = st[r], v1 = st[r1];
            st[r]  = cgate<false>(g, v0, v1);
            st[r1] = cgate<true >(g, v1, v0);
        }
    }
}

// ---- chain exchange with fused U8,U9: new[j] = (U9 U8 psi)[src(j)] ----
// Source wave w' = b | (a<<1) holds (bit8=b, bit9=a). Rows: m8=K8^r1, m9=K9^K8.
template<int K8, int K9>
__device__ __forceinline__ void exch_chain(float2 (&st)[4],
                                           float2 (&buf)[4][4][64],
                                           int l5, int srcLane,
                                           const CG& g8, const CG& g9) {
    #pragma unroll
    for (int r = 0; r < 4; ++r) {
        const int r0 = r & 1, r1 = r >> 1;
        const int sReg = (r0 ^ l5) | ((r1 ^ r0) << 1);
        const float2 s00 = buf[sReg][0][srcLane];   // b=0,a=0
        const float2 s01 = buf[sReg][1][srcLane];   // b=1,a=0
        const float2 s10 = buf[sReg][2][srcLane];   // b=0,a=1
        const float2 s11 = buf[sReg][3][srcLane];   // b=1,a=1
        float2 t0, t1;
        if ((K8 ^ r1) == 0) { t0 = cgate<false>(g8, s00, s01); t1 = cgate<false>(g8, s10, s11); }
        else                { t0 = cgate<true >(g8, s01, s00); t1 = cgate<true >(g8, s11, s10); }
        if ((K9 ^ K8) == 0) st[r] = cgate<false>(g9, t0, t1);
        else                st[r] = cgate<true >(g9, t1, t0);
    }
}

// ---- final exchange: apply U8,U9 only (chain absorbed into weights) ----
template<int K8, int K9>
__device__ __forceinline__ void exch_final(float2 (&st)[4],
                                           float2 (&buf)[4][4][64],
                                           int lane, const CG& g8, const CG& g9) {
    #pragma unroll
    for (int r = 0; r < 4; ++r) {
        const float2 s00 = buf[r][0][lane];
        const float2 s01 = buf[r][1][lane];
        const float2 s10 = buf[r][2][lane];
        const float2 s11 = buf[r][3][lane];
        float2 t0, t1;
        if (K8 == 0) { t0 = cgate<false>(g8, s00, s01); t1 = cgate<false>(g8, s10, s11); }
        else         { t0 = cgate<true >(g8, s01, s00); t1 = cgate<true >(g8, s11, s10); }
        if (K9 == 0) st[r] = cgate<false>(g9, t0, t1);
        else         st[r] = cgate<true >(g9, t1, t0);
    }
}

__global__ __launch_bounds__(256, 8) void cqv_kernel(
    const float* __restrict__ x,
    const float* __restrict__ theta,
    const float* __restrict__ alpha_raw,
    const float* __restrict__ beta_raw,
    const float* __restrict__ head_w,
    const float* __restrict__ head_b,
    const float* __restrict__ logit_scale,
    float* __restrict__ out,
    int batch)
{
    const int lane = threadIdx.x & 63;
    const int wv = threadIdx.x >> 6;           // k8 = wv&1, k9 = wv>>1
    const int s = blockIdx.x;
    if (s >= batch) return;                    // uniform per block

    __shared__ float2 lds[2][4][4][64];        // [buf][reg][wave][lane], 16 KB
    __shared__ float pbuf[4];

    const int l5 = (lane >> 5) & 1;
    const int srcLane = lane ^ ((lane & 31) << 1);
    const int k8 = wv & 1, k9 = (wv >> 1) & 1;

    // ---- per-lane gate params: lane g holds gate g = layer*10 + qubit ----
    const int g = (lane < 30) ? lane : 0;
    const float alpha = log1pf(__expf(alpha_raw[g])) + 1e-6f;
    const float beta  = tanhf(beta_raw[g]);
    const float halfE = 0.5f * PI_F * (alpha * x[s * 49 + g] + beta);
    float cE, sE, cT, sT;
    __sincosf(halfE, &sE, &cE);
    __sincosf(0.5f * theta[g], &sT, &cT);

    float2 st[4];

    // ---- layer 0 on |0..0>: product state. u(0)=A=(ct*ce,-st*se),
    // u(1)=-conj(B)=(ct*se,-st*ce). Params fetched just-in-time (VGPR). ----
    {
        float plr = 1.f, pli = 0.f;            // lane bits 0..5
        #pragma unroll
        for (int q = 0; q < 6; ++q) {
            const float ce = rdlane(cE, q), se = rdlane(sE, q);
            const float ct = rdlane(cT, q), s_t = rdlane(sT, q);
            const bool bq = (lane >> q) & 1;
            const float fr = bq ? ct * se : ct * ce;
            const float fi = bq ? -s_t * ce : -s_t * se;
            const float nr = plr * fr - pli * fi;
            const float ni = plr * fi + pli * fr;
            plr = nr; pli = ni;
        }
        {   // q8 factor (select by k8)
            const float ce = rdlane(cE, 8), se = rdlane(sE, 8);
            const float ct = rdlane(cT, 8), s_t = rdlane(sT, 8);
            const float fr = k8 ? ct * se : ct * ce;
            const float fi = k8 ? -s_t * ce : -s_t * se;
            const float nr = plr * fr - pli * fi, ni = plr * fi + pli * fr;
            plr = nr; pli = ni;
        }
        {   // q9 factor (select by k9)
            const float ce = rdlane(cE, 9), se = rdlane(sE, 9);
            const float ct = rdlane(cT, 9), s_t = rdlane(sT, 9);
            const float fr = k9 ? ct * se : ct * ce;
            const float fi = k9 ? -s_t * ce : -s_t * se;
            const float nr = plr * fr - pli * fi, ni = plr * fi + pli * fr;
            plr = nr; pli = ni;
        }
        const float c6 = rdlane(cE, 6), s6 = rdlane(sE, 6);
        const float ct6 = rdlane(cT, 6), st6 = rdlane(sT, 6);
        const float c7 = rdlane(cE, 7), s7 = rdlane(sE, 7);
        const float ct7 = rdlane(cT, 7), st7 = rdlane(sT, 7);
        #pragma unroll
        for (int r = 0; r < 4; ++r) {
            const float f6r = (r & 1) ? ct6 * s6 : ct6 * c6;
            const float f6i = (r & 1) ? -st6 * c6 : -st6 * s6;
            const float f7r = (r & 2) ? ct7 * s7 : ct7 * c7;
            const float f7i = (r & 2) ? -st7 * c7 : -st7 * s7;
            const float tr_ = f6r * f7r - f6i * f7i;
            const float ti_ = f6r * f7i + f6i * f7r;
            st[r].x = tr_ * plr - ti_ * pli;
            st[r].y = tr_ * pli + ti_ * plr;
        }
    }

    // ---- E0: layer-0 chain, pure permutation (buf 0) ----
    {
        #pragma unroll
        for (int r = 0; r < 4; ++r) lds[0][r][wv][lane] = st[r];
        __syncthreads();
        #pragma unroll
        for (int r = 0; r < 4; ++r) {
            const int r0 = r & 1, r1 = r >> 1;
            const int sReg = (r0 ^ l5) | ((r1 ^ r0) << 1);
            const int sW = (k8 ^ r1) | ((k9 ^ k8) << 1);
            st[r] = lds[0][sReg][sW][srcLane];
        }
    }

#define GATE_PARAMS(GI) \
        const float ce = rdlane(cE, (GI)), se = rdlane(sE, (GI)); \
        const float ct = rdlane(cT, (GI)), s_t = rdlane(sT, (GI));
#define APPLY_LANE_GATE(BASE, Q) { GATE_PARAMS((BASE) + (Q)) \
        lane_gate<Q>(st, lane, ct * ce, -s_t * se, -ct * se, -s_t * ce); }
#define APPLY_REG_GATE(BASE, Q, RB) { GATE_PARAMS((BASE) + (Q)) \
        reg_gate<RB>(st, mkcg(ce, se, ct, s_t)); }
#define APPLY_Q0_Q7(BASE) \
        APPLY_LANE_GATE(BASE, 0) APPLY_LANE_GATE(BASE, 1) APPLY_LANE_GATE(BASE, 2) \
        APPLY_LANE_GATE(BASE, 3) APPLY_LANE_GATE(BASE, 4) APPLY_LANE_GATE(BASE, 5) \
        APPLY_REG_GATE(BASE, 6, 1) APPLY_REG_GATE(BASE, 7, 2)

    // ---- layer 1: q0..q7 in-wave; q8,q9 fused into chain exchange (buf 1) ----
    {
        APPLY_Q0_Q7(10)
        const CG g8 = mkcg(rdlane(cE, 18), rdlane(sE, 18), rdlane(cT, 18), rdlane(sT, 18));
        const CG g9 = mkcg(rdlane(cE, 19), rdlane(sE, 19), rdlane(cT, 19), rdlane(sT, 19));
        #pragma unroll
        for (int r = 0; r < 4; ++r) lds[1][r][wv][lane] = st[r];
        __syncthreads();
        switch (wv) {
            case 0:  exch_chain<0, 0>(st, lds[1], l5, srcLane, g8, g9); break;
            case 1:  exch_chain<1, 0>(st, lds[1], l5, srcLane, g8, g9); break;
            case 2:  exch_chain<0, 1>(st, lds[1], l5, srcLane, g8, g9); break;
            default: exch_chain<1, 1>(st, lds[1], l5, srcLane, g8, g9); break;
        }
    }

    // ---- layer 2: q0..q7 in-wave; q8,q9 same-address exchange (buf 0);
    // final chain absorbed into prefix-XOR head weights below ----
    {
        APPLY_Q0_Q7(20)
        const CG g8 = mkcg(rdlane(cE, 28), rdlane(sE, 28), rdlane(cT, 28), rdlane(sT, 28));
        const CG g9 = mkcg(rdlane(cE, 29), rdlane(sE, 29), rdlane(cT, 29), rdlane(sT, 29));
        #pragma unroll
        for (int r = 0; r < 4; ++r) lds[0][r][wv][lane] = st[r];
        __syncthreads();
        switch (wv) {
            case 0:  exch_final<0, 0>(st, lds[0], lane, g8, g9); break;
            case 1:  exch_final<1, 0>(st, lds[0], lane, g8, g9); break;
            case 2:  exch_final<0, 1>(st, lds[0], lane, g8, g9); break;
            default: exch_final<1, 1>(st, lds[0], lane, g8, g9); break;
        }
    }
#undef GATE_PARAMS
#undef APPLY_LANE_GATE
#undef APPLY_REG_GATE
#undef APPLY_Q0_Q7

    // ---- epilogue: W'(k) = sum_q w_q * (1-2*prefix_q(k)), prefix_q = k0^..^kq
    // (absorbs the final CNOT chain; wave bits k8,k9 enter prefixes 8,9). ----
    float w[10];
    #pragma unroll
    for (int q = 0; q < 10; ++q) w[q] = rdfirst(head_w[q]);
    float wlane = 0.f;
    {
        int pref = 0;
        #pragma unroll
        for (int q = 0; q < 6; ++q) {
            pref ^= (lane >> q) & 1;
            wlane += pref ? -w[q] : w[q];
        }
    }
    const float sPL = (__builtin_popcount(lane & 63) & 1) ? -1.f : 1.f;
    float acc = 0.f, psum = 0.f;
    #pragma unroll
    for (int r = 0; r < 4; ++r) {
        const float pw = st[r].x * st[r].x + st[r].y * st[r].y;
        const int p0 = r & 1, p1 = p0 ^ (r >> 1);
        const float wr = (p0 ? -w[6] : w[6]) + (p1 ? -w[7] : w[7])
                       + ((p1 ^ k8) ? -w[8] : w[8]) + ((p1 ^ k8 ^ k9) ? -w[9] : w[9]);
        psum += pw;
        acc = fmaf(wr, pw, acc);
    }
    float partial = fmaf(wlane, psum, sPL * acc);
    #pragma unroll
    for (int off = 32; off >= 1; off >>= 1) partial += __shfl_xor(partial, off);

    if (lane == 0) pbuf[wv] = partial;
    __syncthreads();
    if (threadIdx.x == 0) {
        const float scale = fminf(fmaxf(logit_scale[0], 0.5f), 80.f);
        const float raw = pbuf[0] + pbuf[1] + pbuf[2] + pbuf[3] + head_b[0];
        out[s] = fminf(fmaxf(scale * raw, -30.f), 30.f);
    }
}

extern "C" void kernel_launch(void* const* d_in, const int* in_sizes, int n_in,
                              void* d_out, int out_size, void* d_ws, size_t ws_size,
                              hipStream_t stream) {
    const int B = in_sizes[0] / 49;          // BATCH = 2048
    dim3 block(256);                         // 4 waves = 1 sample
    dim3 grid(B);
    cqv_kernel<<<grid, block, 0, stream>>>(
        (const float*)d_in[0], (const float*)d_in[1], (const float*)d_in[2],
        (const float*)d_in[3], (const float*)d_in[4], (const float*)d_in[5],
        (const float*)d_in[6], (float*)d_out, B);
}

// Round 9
// 80.433 us; speedup vs baseline: 1.0498x; 1.0498x over previous
//
#include <hip/hip_runtime.h>
#include <math.h>

// === r9 = r7 (best: 79.7us, absmax 0) + micro-cuts; r8's 4-wave split
// REGRESSED (84.4) and is reverted. ===
// TWO waves per sample, ONE sample per block (block=128). Amplitude i:
//   bits 0..5 -> lane, bits 6..8 -> register (8 float2/lane), bit 9 -> wave.
// Layers: fused U_q = RX(theta)*RY(enc); CNOT chain = permutation
// src(j) = j ^ ((j&511)<<1). Layer-0 acts on |0..0> -> product state.
// Layer-2's FINAL CNOT chain is absorbed into the head weights via
// prefix-XOR signs; the last LDS exchange is a same-address pair swap (q9).
// Micro-cuts this round: exact-grid (no bounds branch), __expf/__logf-based
// softplus+tanh in the prologue (libm tanhf/log1pf were ~30-inst calls).
// Evidence trail: r4 DS->VALU neutral (issue-bound), r5 pk_fma (-28% insts,
// win), r6 2-wave split (win), r7 barrier decoupling + weight-absorbed
// final chain (win), r8 4-wave split (regression -> reverted).

#define PI_F 3.14159265358979323846f

typedef unsigned v2u __attribute__((ext_vector_type(2)));

#if defined(__has_builtin)
#if __has_builtin(__builtin_amdgcn_permlane16_swap)
#define HAVE_PL16 1
#endif
#if __has_builtin(__builtin_amdgcn_permlane32_swap)
#define HAVE_PL32 1
#endif
#endif

__device__ __forceinline__ float rdlane(float v, int l) {
    return __int_as_float(__builtin_amdgcn_readlane(__float_as_int(v), l));
}

// ---- VALU-pipe lane^mask partner fetch (verified r4-r7, absmax 0) ----
__device__ __forceinline__ float xor1p(float v) {
    return __int_as_float(__builtin_amdgcn_update_dpp(
        0, __float_as_int(v), 0xB1, 0xF, 0xF, true));
}
__device__ __forceinline__ float xor2p(float v) {
    return __int_as_float(__builtin_amdgcn_update_dpp(
        0, __float_as_int(v), 0x4E, 0xF, 0xF, true));
}
__device__ __forceinline__ float xor4p(float v) {   // xor7 ∘ xor3 = xor4
    int t = __builtin_amdgcn_update_dpp(0, __float_as_int(v), 0x1B, 0xF, 0xF, true);
    t = __builtin_amdgcn_update_dpp(0, t, 0x141, 0xF, 0xF, true);
    return __int_as_float(t);
}
__device__ __forceinline__ float xor8p(float v) {   // row_ror:8
    return __int_as_float(__builtin_amdgcn_update_dpp(
        0, __float_as_int(v), 0x128, 0xF, 0xF, true));
}
__device__ __forceinline__ float xor16p(float v, bool hi) {
#ifdef HAVE_PL16
    v2u r = __builtin_amdgcn_permlane16_swap(
        (unsigned)__float_as_int(v), (unsigned)__float_as_int(v), false, false);
    return __int_as_float((int)(hi ? r.x : r.y));
#else
    return __shfl_xor(v, 16);
#endif
}
__device__ __forceinline__ float xor32p(float v, bool hi) {
#ifdef HAVE_PL32
    v2u r = __builtin_amdgcn_permlane32_swap(
        (unsigned)__float_as_int(v), (unsigned)__float_as_int(v), false, false);
    return __int_as_float((int)(hi ? r.x : r.y));
#else
    return __shfl_xor(v, 32);
#endif
}

template<int Q>
__device__ __forceinline__ float lane_xor(float v, bool hi) {
    if constexpr (Q == 0) return xor1p(v);
    else if constexpr (Q == 1) return xor2p(v);
    else if constexpr (Q == 2) return xor4p(v);
    else if constexpr (Q == 3) return xor8p(v);
    else if constexpr (Q == 4) return xor16p(v, hi);
    else return xor32p(v, hi);
}

// ---- packed complex gate core (verified r5-r7, absmax 0) ----
// cgate<false>(v,w) = A v + B w ; cgate<true>(v,w) = conj(A) v - conj(B) w
template<bool NEG>
__device__ __forceinline__ float2 cgate(const float2 ar2, const float2 ai2,
                                        const float2 br2, const float2 bi2,
                                        const float2 v, const float2 w) {
    float2 acc;
    asm("v_pk_mul_f32 %0, %1, %2" : "=v"(acc) : "v"(ar2), "v"(v));
    if constexpr (!NEG) {
        asm("v_pk_fma_f32 %0, %1, %2, %0 op_sel:[0,1,0] op_sel_hi:[1,0,1] neg_lo:[0,1,0]"
            : "+v"(acc) : "v"(ai2), "v"(v));
        asm("v_pk_fma_f32 %0, %1, %2, %0" : "+v"(acc) : "v"(br2), "v"(w));
    } else {
        asm("v_pk_fma_f32 %0, %1, %2, %0 op_sel:[0,1,0] op_sel_hi:[1,0,1] neg_lo:[1,1,0] neg_hi:[1,0,0]"
            : "+v"(acc) : "v"(ai2), "v"(v));
        asm("v_pk_fma_f32 %0, %1, %2, %0 neg_lo:[1,0,0] neg_hi:[1,0,0]"
            : "+v"(acc) : "v"(br2), "v"(w));
    }
    asm("v_pk_fma_f32 %0, %1, %2, %0 op_sel:[0,1,0] op_sel_hi:[1,0,1] neg_lo:[0,1,0]"
        : "+v"(acc) : "v"(bi2), "v"(w));
    return acc;
}

template<int Q>
__device__ __forceinline__ void lane_gate(float2 (&st)[8], int lane,
                                          float ar, float ai, float br, float bi) {
    const bool hi = (lane & (1 << Q)) != 0;
    const float aiL = hi ? -ai : ai;
    const float brL = hi ? -br : br;
    const float2 ar2 = make_float2(ar, ar);
    const float2 ai2 = make_float2(aiL, aiL);
    const float2 br2 = make_float2(brL, brL);
    const float2 bi2 = make_float2(bi, bi);
    #pragma unroll
    for (int r = 0; r < 8; ++r) {
        float2 p;
        p.x = lane_xor<Q>(st[r].x, hi);
        p.y = lane_xor<Q>(st[r].y, hi);
        st[r] = cgate<false>(ar2, ai2, br2, bi2, st[r], p);
    }
}

template<int RB>
__device__ __forceinline__ void reg_gate(float2 (&st)[8],
                                         float ar, float ai, float br, float bi) {
    const float2 ar2 = make_float2(ar, ar);
    const float2 ai2 = make_float2(ai, ai);
    const float2 br2 = make_float2(br, br);
    const float2 bi2 = make_float2(bi, bi);
    #pragma unroll
    for (int r = 0; r < 8; ++r) {
        if ((r & RB) == 0) {
            const int r1 = r | RB;
            const float2 v0 = st[r], v1 = st[r1];
            st[r]  = cgate<false>(ar2, ai2, br2, bi2, v0, v1);
            st[r1] = cgate<true >(ar2, ai2, br2, bi2, v1, v0);
        }
    }
}

__global__ __launch_bounds__(128, 4) void cqv_kernel(
    const float* __restrict__ x,
    const float* __restrict__ theta,
    const float* __restrict__ alpha_raw,
    const float* __restrict__ beta_raw,
    const float* __restrict__ head_w,
    const float* __restrict__ head_b,
    const float* __restrict__ logit_scale,
    float* __restrict__ out,
    int batch)
{
    const int lane = threadIdx.x & 63;
    const int wv = threadIdx.x >> 6;           // qubit-9 bit of this wave
    const int s = blockIdx.x;                  // one sample per block (grid exact)

    // [buf][reg][wv][lane] ; + epilogue partials. 8KB + 8B.
    __shared__ float2 lds[2][8][2][64];
    __shared__ float pbuf[2];

    const int l5 = (lane >> 5) & 1;
    const int srcLane = lane ^ ((lane & 31) << 1);

    // ---- per-lane gate params: lane g holds gate g = layer*10 + qubit ----
    const int g = (lane < 30) ? lane : 0;
    // softplus via __expf/__logf; tanh via (e^{2x}-1)/(e^{2x}+1) (~1e-6 err,
    // threshold 4e-3; libm tanhf/log1pf were ~30-inst calls)
    const float alpha = __logf(1.f + __expf(alpha_raw[g])) + 1e-6f;
    const float e2b   = __expf(2.f * beta_raw[g]);
    const float beta  = (e2b - 1.f) / (e2b + 1.f);
    const float halfE = 0.5f * PI_F * (alpha * x[s * 49 + g] + beta);
    float cE, sE, cT, sT;
    __sincosf(halfE, &sE, &cE);
    __sincosf(0.5f * theta[g], &sT, &cT);

    float2 st[8];

    // ---- layer 0 on |0..0>: product state, q9 factor chosen by wv ----
    {
        float u0r[10], u0i[10], u1r[10], u1i[10];
        #pragma unroll
        for (int q = 0; q < 10; ++q) {
            const float ce = rdlane(cE, q), se = rdlane(sE, q);
            const float ct = rdlane(cT, q), s_t = rdlane(sT, q);
            u0r[q] = ct * ce;  u0i[q] = -s_t * se;   // A
            u1r[q] = ct * se;  u1i[q] = -s_t * ce;   // -conj(B)
        }
        float plr = 1.f, pli = 0.f;                  // lane bits 0..5
        #pragma unroll
        for (int q = 0; q < 6; ++q) {
            const bool bq = (lane >> q) & 1;
            const float wr = bq ? u1r[q] : u0r[q];
            const float wi = bq ? u1i[q] : u0i[q];
            const float nr = plr * wr - pli * wi;
            const float ni = plr * wi + pli * wr;
            plr = nr; pli = ni;
        }
        const float w9r = wv ? u1r[9] : u0r[9], w9i = wv ? u1i[9] : u0i[9];
        float t67r[4], t67i[4], t89r[2], t89i[2];
        #pragma unroll
        for (int a = 0; a < 4; ++a) {
            const float w6r = (a & 1) ? u1r[6] : u0r[6], w6i = (a & 1) ? u1i[6] : u0i[6];
            const float w7r = (a & 2) ? u1r[7] : u0r[7], w7i = (a & 2) ? u1i[7] : u0i[7];
            t67r[a] = w6r * w7r - w6i * w7i;  t67i[a] = w6r * w7i + w6i * w7r;
        }
        #pragma unroll
        for (int k = 0; k < 2; ++k) {
            const float w8r = k ? u1r[8] : u0r[8], w8i = k ? u1i[8] : u0i[8];
            t89r[k] = w8r * w9r - w8i * w9i;  t89i[k] = w8r * w9i + w8i * w9r;
        }
        #pragma unroll
        for (int r = 0; r < 8; ++r) {
            const float ar = t67r[r & 3] * t89r[r >> 2] - t67i[r & 3] * t89i[r >> 2];
            const float ai = t67r[r & 3] * t89i[r >> 2] + t67i[r & 3] * t89r[r >> 2];
            st[r].x = ar * plr - ai * pli;
            st[r].y = ar * pli + ai * plr;
        }
    }

    // ---- layer-0 CNOT chain: pure cross-wave permutation (buf 0) ----
    {
        #pragma unroll
        for (int r = 0; r < 8; ++r) lds[0][r][wv][lane] = st[r];
        __syncthreads();
        #pragma unroll
        for (int r = 0; r < 8; ++r) {
            const int sReg = (r ^ ((r & 3) << 1)) ^ l5;
            const int k9 = wv ^ (r >> 2);
            st[r] = lds[0][sReg][k9][srcLane];
        }
    }

#define GATE_PARAMS(BASE, Q) \
        const float ce = rdlane(cE, (BASE) + (Q)), se = rdlane(sE, (BASE) + (Q)); \
        const float ct = rdlane(cT, (BASE) + (Q)), s_t = rdlane(sT, (BASE) + (Q));
#define APPLY_LANE_GATE(BASE, Q) { GATE_PARAMS(BASE, Q) \
        lane_gate<Q>(st, lane, ct * ce, -s_t * se, -ct * se, -s_t * ce); }
#define APPLY_REG_GATE(BASE, Q, RB) { GATE_PARAMS(BASE, Q) \
        reg_gate<RB>(st, ct * ce, -s_t * se, -ct * se, -s_t * ce); }
#define APPLY_Q0_Q8(BASE) \
        APPLY_LANE_GATE(BASE, 0) APPLY_LANE_GATE(BASE, 1) APPLY_LANE_GATE(BASE, 2) \
        APPLY_LANE_GATE(BASE, 3) APPLY_LANE_GATE(BASE, 4) APPLY_LANE_GATE(BASE, 5) \
        APPLY_REG_GATE(BASE, 6, 1) APPLY_REG_GATE(BASE, 7, 2) APPLY_REG_GATE(BASE, 8, 4)

    // ---- layer 1: q0..q8 in-wave; q9 fused into CNOT exchange (buf 1) ----
    {
        APPLY_Q0_Q8(10)
        GATE_PARAMS(10, 9)
        const float ar = ct * ce, ai = -s_t * se, br = -ct * se, bi = -s_t * ce;
        const float2 ar2 = make_float2(ar, ar), ai2 = make_float2(ai, ai);
        const float2 br2 = make_float2(br, br), bi2 = make_float2(bi, bi);
        #pragma unroll
        for (int r = 0; r < 8; ++r) lds[1][r][wv][lane] = st[r];
        __syncthreads();
        #pragma unroll
        for (int r = 0; r < 8; ++r) {
            const int sReg = (r ^ ((r & 3) << 1)) ^ l5;
            const int k9 = wv ^ (r >> 2);
            const float2 v = lds[1][sReg][k9][srcLane];
            const float2 w = lds[1][sReg][k9 ^ 1][srcLane];
            if (k9 == 0) st[r] = cgate<false>(ar2, ai2, br2, bi2, v, w);
            else         st[r] = cgate<true >(ar2, ai2, br2, bi2, v, w);
        }
    }

    // ---- layer 2: q0..q8 in-wave; q9 = same-address pair swap (buf 0,
    // safe: L1's barrier orders all buf-0 reads before this write). The
    // final CNOT chain is absorbed into the head weights below. ----
    {
        APPLY_Q0_Q8(20)
        GATE_PARAMS(20, 9)
        const float ar = ct * ce, ai = -s_t * se, br = -ct * se, bi = -s_t * ce;
        const float2 ar2 = make_float2(ar, ar), ai2 = make_float2(ai, ai);
        const float2 br2 = make_float2(br, br), bi2 = make_float2(bi, bi);
        #pragma unroll
        for (int r = 0; r < 8; ++r) lds[0][r][wv][lane] = st[r];
        __syncthreads();
        #pragma unroll
        for (int r = 0; r < 8; ++r) {
            const float2 w = lds[0][r][wv ^ 1][lane];   // partner amplitude
            if (wv == 0) st[r] = cgate<false>(ar2, ai2, br2, bi2, st[r], w);
            else         st[r] = cgate<true >(ar2, ai2, br2, bi2, st[r], w);
        }
    }
#undef GATE_PARAMS
#undef APPLY_LANE_GATE
#undef APPLY_REG_GATE
#undef APPLY_Q0_Q8

    // ---- epilogue with permuted weights W'(k) = sum_q w_q*(1-2*prefix_q(k)),
    // prefix_q(k) = k_0^..^k_q  (absorbs the final CNOT chain). ----
    float w[10];
    #pragma unroll
    for (int q = 0; q < 10; ++q) w[q] = head_w[q];
    float wlane = 0.f;
    {
        int pref = 0;
        #pragma unroll
        for (int q = 0; q < 6; ++q) {
            pref ^= (lane >> q) & 1;
            wlane += pref ? -w[q] : w[q];
        }
    }
    const float sPL = ((__builtin_popcount(lane & 63) & 1) ? -1.f : 1.f);
    float acc = 0.f, psum = 0.f;
    #pragma unroll
    for (int r = 0; r < 8; ++r) {
        const float pw = st[r].x * st[r].x + st[r].y * st[r].y;
        const int p0 = r & 1, p1 = p0 ^ ((r >> 1) & 1), p2 = p1 ^ ((r >> 2) & 1);
        const float wr = (p0 ? -w[6] : w[6]) + (p1 ? -w[7] : w[7])
                       + (p2 ? -w[8] : w[8]) + ((p2 ^ wv) ? -w[9] : w[9]);
        psum += pw;
        acc = fmaf(wr, pw, acc);
    }
    float partial = fmaf(wlane, psum, sPL * acc);
    #pragma unroll
    for (int off = 32; off >= 1; off >>= 1) partial += __shfl_xor(partial, off);

    if (lane == 0) pbuf[wv] = partial;
    __syncthreads();
    if (threadIdx.x == 0) {
        const float scale = fminf(fmaxf(logit_scale[0], 0.5f), 80.f);
        const float raw = pbuf[0] + pbuf[1] + head_b[0];
        out[s] = fminf(fmaxf(scale * raw, -30.f), 30.f);
    }
}

extern "C" void kernel_launch(void* const* d_in, const int* in_sizes, int n_in,
                              void* d_out, int out_size, void* d_ws, size_t ws_size,
                              hipStream_t stream) {
    const int B = in_sizes[0] / 49;          // BATCH = 2048
    dim3 block(128);                         // 2 waves = 1 sample
    dim3 grid(B);
    cqv_kernel<<<grid, block, 0, stream>>>(
        (const float*)d_in[0], (const float*)d_in[1], (const float*)d_in[2],
        (const float*)d_in[3], (const float*)d_in[4], (const float*)d_in[5],
        (const float*)d_in[6], (float*)d_out, B);
}